// Round 2
// baseline (893.343 us; speedup 1.0000x reference)
//
#include <hip/hip_runtime.h>
#include <hip/hip_bf16.h>
#include <math.h>

// Problem constants (from reference)
#define BATCH   64
#define NNODES  256
#define HID     256
#define HEADS   4
#define CDIM    64
#define NEDGES  8192
#define NEG_SLOPE 0.2f
#define EPS_BN 1e-5f

typedef __bf16 bf16_t;
typedef __bf16 bf16x8 __attribute__((ext_vector_type(8)));
typedef float  f32x4  __attribute__((ext_vector_type(4)));

__device__ __forceinline__ float gelu_f(float x) {
    return 0.5f * x * (1.0f + erff(x * 0.70710678118654752440f));
}

// ---------------------------------------------------------------------------
// CSR build: one block, 256 threads. edge_index = [src[E], dst[E]] int32.
// ---------------------------------------------------------------------------
__global__ __launch_bounds__(256) void csr_kernel(const int* __restrict__ ei,
                                                  int* __restrict__ noff,
                                                  int* __restrict__ csrc) {
    __shared__ int cnt[NNODES];
    __shared__ int off_s[NNODES + 1];
    const int tid = threadIdx.x;
    cnt[tid] = 0;
    __syncthreads();
    for (int e = tid; e < NEDGES; e += 256) atomicAdd(&cnt[ei[NEDGES + e]], 1);
    __syncthreads();
    if (tid == 0) {
        int s = 0;
        for (int i = 0; i < NNODES; ++i) { off_s[i] = s; s += cnt[i]; }
        off_s[NNODES] = s;
    }
    __syncthreads();
    cnt[tid] = off_s[tid];        // reuse as cursor
    noff[tid] = off_s[tid];
    if (tid == 0) noff[NNODES] = off_s[NNODES];
    __syncthreads();
    for (int e = tid; e < NEDGES; e += 256) {
        int d = ei[NEDGES + e];
        int p = atomicAdd(&cnt[d], 1);
        csrc[p] = ei[e];
    }
}

// ---------------------------------------------------------------------------
// MFMA bf16 GEMM on fp32 data:  C[M x 256] = A[M x K] @ B[K x 256] (+epilogue)
// A,B fp32 in HBM -> converted to bf16 at LDS staging; fp32 MFMA accumulate;
// fp32 store. Block 256 threads (4 waves). Tile 64(M) x 64(N), BK=32.
// mode 0: C = acc + bias;  mode 1: C = gelu(BN(acc + bias))
// MFMA lane layouts (verified, guide §3):
//   A frag: A[m=lane&15][k=(lane>>4)*8 + j]
//   B frag: B[k=(lane>>4)*8 + j][n=lane&15]
//   C/D   : row=(lane>>4)*4+reg, col=lane&15
// ---------------------------------------------------------------------------
#define BM 64
#define BN 64
#define BK 32
#define LDSTR 56   // padded LDS row stride (112 B: 16B-aligned rows)

__global__ __launch_bounds__(256) void gemm_kernel(
        const float* __restrict__ A, const float* __restrict__ Bm,
        float* __restrict__ C, int M, int K,
        const float* __restrict__ bias,
        const float* __restrict__ g, const float* __restrict__ be,
        const float* __restrict__ mu, const float* __restrict__ var,
        int mode) {
    __shared__ bf16_t As[BM][LDSTR];
    __shared__ bf16_t Bs[BN][LDSTR];   // stored transposed: Bs[n][k]
    const int tid  = threadIdx.x;
    const int lane = tid & 63;
    const int w    = tid >> 6;
    const int m0   = blockIdx.y * BM;
    const int n0   = blockIdx.x * BN;
    const int NCOL = 256;

    f32x4 acc[4];
    #pragma unroll
    for (int t = 0; t < 4; ++t) acc[t] = (f32x4){0.f, 0.f, 0.f, 0.f};

    const int ar = tid >> 2;          // A-stage row   0..63
    const int ak = (tid & 3) * 8;     // A-stage k off 0/8/16/24
    const int bg = (tid & 7) * 8;     // B-stage n group
    const int bk = tid >> 3;          // B-stage k row 0..31

    for (int k0 = 0; k0 < K; k0 += BK) {
        const float* ap = A + (size_t)(m0 + ar) * K + k0 + ak;
        f32x4 a0 = *(const f32x4*)ap;
        f32x4 a1 = *(const f32x4*)(ap + 4);
        bf16x8 av;
        #pragma unroll
        for (int j = 0; j < 4; ++j) { av[j] = (bf16_t)a0[j]; av[4 + j] = (bf16_t)a1[j]; }
        *(bf16x8*)(&As[ar][ak]) = av;

        const float* bp = Bm + (size_t)(k0 + bk) * NCOL + n0 + bg;
        f32x4 b0 = *(const f32x4*)bp;
        f32x4 b1 = *(const f32x4*)(bp + 4);
        #pragma unroll
        for (int j = 0; j < 4; ++j) {
            Bs[bg + j][bk]     = (bf16_t)b0[j];
            Bs[bg + 4 + j][bk] = (bf16_t)b1[j];
        }
        __syncthreads();

        bf16x8 af = *(const bf16x8*)(&As[w * 16 + (lane & 15)][(lane >> 4) * 8]);
        #pragma unroll
        for (int t = 0; t < 4; ++t) {
            bf16x8 bfv = *(const bf16x8*)(&Bs[t * 16 + (lane & 15)][(lane >> 4) * 8]);
            acc[t] = __builtin_amdgcn_mfma_f32_16x16x32_bf16(af, bfv, acc[t], 0, 0, 0);
        }
        __syncthreads();
    }

    const int qr = (lane >> 4) * 4;
    const int cn = lane & 15;
    #pragma unroll
    for (int t = 0; t < 4; ++t) {
        const int n = n0 + t * 16 + cn;
        const float bv = bias[n];
        float scale = 1.0f, shift = 0.0f;
        if (mode == 1) {
            float s = g[n] * rsqrtf(var[n] + EPS_BN);
            scale = s;
            shift = be[n] - mu[n] * s;
        }
        #pragma unroll
        for (int r = 0; r < 4; ++r) {
            const int m = m0 + w * 16 + qr + r;
            float val = acc[t][r] + bv;
            if (mode == 1) val = gelu_f(val * scale + shift);
            C[(size_t)m * NCOL + n] = val;
        }
    }
}

// ---------------------------------------------------------------------------
// GATv2 edge softmax + aggregate, fused epilogue gelu(out + bo).
// Grid (NNODES, BATCH), block 256 = 4 waves, wave w == head w, lane == channel.
// Two passes over CSR neighbors: (1) per-head max logit, (2) exp/sum/aggregate.
// ---------------------------------------------------------------------------
__global__ __launch_bounds__(256) void edge_kernel(
        const float* __restrict__ XL, const float* __restrict__ XR,
        const float* __restrict__ att, const float* __restrict__ bo,
        const int* __restrict__ noff, const int* __restrict__ csrc,
        float* __restrict__ Hout) {
    const int i   = blockIdx.x;
    const int b   = blockIdx.y;
    const int tid = threadIdx.x;
    const size_t base = (size_t)b * NNODES * HID;

    const float attv = att[tid];       // att[h][c], h=tid>>6, c=tid&63
    const float xi   = XR[base + (size_t)i * HID + tid];
    const int s0 = noff[i], s1 = noff[i + 1];

    float mmax = -1e30f;
    for (int e = s0; e < s1; ++e) {
        const int j = csrc[e];
        const float xj = XL[base + (size_t)j * HID + tid];
        float v = xi + xj;
        v = (v > 0.f) ? v : NEG_SLOPE * v;
        float p = attv * v;
        #pragma unroll
        for (int mask = 32; mask >= 1; mask >>= 1) p += __shfl_xor(p, mask, 64);
        mmax = fmaxf(mmax, p);
    }

    float den = 0.f, acc = 0.f;
    for (int e = s0; e < s1; ++e) {
        const int j = csrc[e];
        const float xj = XL[base + (size_t)j * HID + tid];
        float v = xi + xj;
        v = (v > 0.f) ? v : NEG_SLOPE * v;
        float p = attv * v;
        #pragma unroll
        for (int mask = 32; mask >= 1; mask >>= 1) p += __shfl_xor(p, mask, 64);
        const float wv = expf(p - mmax);
        den += wv;
        acc += wv * xj;
    }

    float outv = (s1 > s0) ? (acc / (den + 1e-16f)) : 0.0f;
    outv += bo[tid];
    Hout[base + (size_t)i * HID + tid] = gelu_f(outv);
}

// ---------------------------------------------------------------------------
// Mean-pool over nodes: pooled[b][f] = mean_n H1[b][n][f]
// ---------------------------------------------------------------------------
__global__ __launch_bounds__(256) void pool_kernel(const float* __restrict__ H1,
                                                   float* __restrict__ pooled) {
    const int b = blockIdx.x, f = threadIdx.x;
    const float* p = H1 + (size_t)b * NNODES * HID + f;
    float s = 0.f;
    for (int n = 0; n < NNODES; ++n) s += p[(size_t)n * HID];
    pooled[b * HID + f] = s * (1.0f / (float)NNODES);
}

// ---------------------------------------------------------------------------
// Output proj: out = gelu(BN(pooled @ W2 + b2)). Tiny (64x256x256), fp32.
// ---------------------------------------------------------------------------
__global__ __launch_bounds__(256) void final_kernel(
        const float* __restrict__ pooled, const float* __restrict__ W2,
        const float* __restrict__ b2, const float* __restrict__ g2,
        const float* __restrict__ be2, const float* __restrict__ m2,
        const float* __restrict__ v2, float* __restrict__ out) {
    const int b = blockIdx.x, f = threadIdx.x;
    const float* pr = pooled + b * HID;
    float s = 0.f;
    for (int k = 0; k < HID; ++k) s += pr[k] * W2[(size_t)k * HID + f];
    s += b2[f];
    const float scale = g2[f] * rsqrtf(v2[f] + EPS_BN);
    s = (s - m2[f]) * scale + be2[f];
    out[b * HID + f] = gelu_f(s);
}

// ---------------------------------------------------------------------------
extern "C" void kernel_launch(void* const* d_in, const int* in_sizes, int n_in,
                              void* d_out, int out_size, void* d_ws, size_t ws_size,
                              hipStream_t stream) {
    const float* x    = (const float*)d_in[0];
    const int*   ei   = (const int*)d_in[1];
    const float* W1   = (const float*)d_in[2];
    const float* b1   = (const float*)d_in[3];
    const float* g1   = (const float*)d_in[4];
    const float* be1  = (const float*)d_in[5];
    const float* m1   = (const float*)d_in[6];
    const float* v1   = (const float*)d_in[7];
    const float* Wl0  = (const float*)d_in[8];
    const float* bl0  = (const float*)d_in[9];
    const float* Wr0  = (const float*)d_in[10];
    const float* br0  = (const float*)d_in[11];
    const float* att0 = (const float*)d_in[12];
    const float* bo0  = (const float*)d_in[13];
    const float* Wl1  = (const float*)d_in[14];
    const float* bl1  = (const float*)d_in[15];
    const float* Wr1  = (const float*)d_in[16];
    const float* br1  = (const float*)d_in[17];
    const float* att1 = (const float*)d_in[18];
    const float* bo1  = (const float*)d_in[19];
    const float* W2   = (const float*)d_in[20];
    const float* b2   = (const float*)d_in[21];
    const float* g2   = (const float*)d_in[22];
    const float* be2  = (const float*)d_in[23];
    const float* m2   = (const float*)d_in[24];
    const float* v2   = (const float*)d_in[25];

    char* ws = (char*)d_ws;
    const size_t SZ_H = (size_t)BATCH * NNODES * HID * sizeof(float);  // 16 MB
    int*   noff   = (int*)ws;                          //   2 KB (257 ints)
    int*   csrc   = (int*)(ws + 2048);                 //  32 KB
    float* H1buf  = (float*)(ws + 2048 + 32768);
    float* XL     = (float*)((char*)H1buf + SZ_H);
    float* XR     = (float*)((char*)XL + SZ_H);
    float* H2buf  = (float*)((char*)XR + SZ_H);
    float* pooled = (float*)((char*)H2buf + SZ_H);     //  64 KB

    const int M = BATCH * NNODES;                       // 16384
    dim3 ggrid(HID / BN, M / BM);                       // (4, 256)

    csr_kernel<<<1, 256, 0, stream>>>(ei, noff, csrc);

    // node_proj: H1buf = gelu(BN(x @ W1 + b1))
    gemm_kernel<<<ggrid, 256, 0, stream>>>(x, W1, H1buf, M, NNODES * 3,
                                           b1, g1, be1, m1, v1, 1);
    // GATv2 layer 0 projections
    gemm_kernel<<<ggrid, 256, 0, stream>>>(H1buf, Wl0, XL, M, HID,
                                           bl0, nullptr, nullptr, nullptr, nullptr, 0);
    gemm_kernel<<<ggrid, 256, 0, stream>>>(H1buf, Wr0, XR, M, HID,
                                           br0, nullptr, nullptr, nullptr, nullptr, 0);
    edge_kernel<<<dim3(NNODES, BATCH), 256, 0, stream>>>(XL, XR, att0, bo0,
                                                         noff, csrc, H2buf);
    // GATv2 layer 1 projections
    gemm_kernel<<<ggrid, 256, 0, stream>>>(H2buf, Wl1, XL, M, HID,
                                           bl1, nullptr, nullptr, nullptr, nullptr, 0);
    gemm_kernel<<<ggrid, 256, 0, stream>>>(H2buf, Wr1, XR, M, HID,
                                           br1, nullptr, nullptr, nullptr, nullptr, 0);
    edge_kernel<<<dim3(NNODES, BATCH), 256, 0, stream>>>(XL, XR, att1, bo1,
                                                         noff, csrc, H1buf);

    pool_kernel<<<BATCH, 256, 0, stream>>>(H1buf, pooled);
    final_kernel<<<BATCH, 256, 0, stream>>>(pooled, W2, b2, g2, be2, m2, v2,
                                            (float*)d_out);
}

// Round 3
// 427.999 us; speedup vs baseline: 2.0873x; 2.0873x over previous
//
#include <hip/hip_runtime.h>
#include <hip/hip_bf16.h>
#include <math.h>

// Problem constants (from reference)
#define BATCH   64
#define NNODES  256
#define HID     256
#define HEADS   4
#define CDIM    64
#define NEDGES  8192
#define NEG_SLOPE 0.2f
#define EPS_BN 1e-5f

typedef __bf16 bf16_t;
typedef __bf16 bf16x8 __attribute__((ext_vector_type(8)));
typedef float  f32x4  __attribute__((ext_vector_type(4)));

__device__ __forceinline__ float gelu_f(float x) {
    return 0.5f * x * (1.0f + erff(x * 0.70710678118654752440f));
}

// ---------------------------------------------------------------------------
// CSR build: one block, 256 threads. edge_index = [src[E], dst[E]] int32.
// ---------------------------------------------------------------------------
__global__ __launch_bounds__(256) void csr_kernel(const int* __restrict__ ei,
                                                  int* __restrict__ noff,
                                                  int* __restrict__ csrc) {
    __shared__ int cnt[NNODES];
    __shared__ int off_s[NNODES + 1];
    const int tid = threadIdx.x;
    cnt[tid] = 0;
    __syncthreads();
    for (int e = tid; e < NEDGES; e += 256) atomicAdd(&cnt[ei[NEDGES + e]], 1);
    __syncthreads();
    if (tid == 0) {
        int s = 0;
        for (int i = 0; i < NNODES; ++i) { off_s[i] = s; s += cnt[i]; }
        off_s[NNODES] = s;
    }
    __syncthreads();
    cnt[tid] = off_s[tid];        // reuse as cursor
    noff[tid] = off_s[tid];
    if (tid == 0) noff[NNODES] = off_s[NNODES];
    __syncthreads();
    for (int e = tid; e < NEDGES; e += 256) {
        int d = ei[NEDGES + e];
        int p = atomicAdd(&cnt[d], 1);
        csrc[p] = ei[e];
    }
}

// ---------------------------------------------------------------------------
// MFMA bf16 GEMM on fp32 data:  C[M x 256] = A[M x K] @ B[K x 256] (+epilogue)
// Block 256 threads (4 waves). Tile 64(M) x 64(N), BK=32.
// mode 0: C = acc + bias;  mode 1: C = gelu(BN(acc + bias))
// ---------------------------------------------------------------------------
#define BM 64
#define BN 64
#define BK 32
#define LDSTR 56   // padded LDS row stride

__global__ __launch_bounds__(256) void gemm_kernel(
        const float* __restrict__ A, const float* __restrict__ Bm,
        float* __restrict__ C, int M, int K,
        const float* __restrict__ bias,
        const float* __restrict__ g, const float* __restrict__ be,
        const float* __restrict__ mu, const float* __restrict__ var,
        int mode) {
    __shared__ bf16_t As[BM][LDSTR];
    __shared__ bf16_t Bs[BN][LDSTR];   // stored transposed: Bs[n][k]
    const int tid  = threadIdx.x;
    const int lane = tid & 63;
    const int w    = tid >> 6;
    const int m0   = blockIdx.y * BM;
    const int n0   = blockIdx.x * BN;
    const int NCOL = 256;

    f32x4 acc[4];
    #pragma unroll
    for (int t = 0; t < 4; ++t) acc[t] = (f32x4){0.f, 0.f, 0.f, 0.f};

    const int ar = tid >> 2;          // A-stage row   0..63
    const int ak = (tid & 3) * 8;     // A-stage k off 0/8/16/24
    const int bg = (tid & 7) * 8;     // B-stage n group
    const int bk = tid >> 3;          // B-stage k row 0..31

    for (int k0 = 0; k0 < K; k0 += BK) {
        const float* ap = A + (size_t)(m0 + ar) * K + k0 + ak;
        f32x4 a0 = *(const f32x4*)ap;
        f32x4 a1 = *(const f32x4*)(ap + 4);
        bf16x8 av;
        #pragma unroll
        for (int j = 0; j < 4; ++j) { av[j] = (bf16_t)a0[j]; av[4 + j] = (bf16_t)a1[j]; }
        *(bf16x8*)(&As[ar][ak]) = av;

        const float* bp = Bm + (size_t)(k0 + bk) * NCOL + n0 + bg;
        f32x4 b0 = *(const f32x4*)bp;
        f32x4 b1 = *(const f32x4*)(bp + 4);
        #pragma unroll
        for (int j = 0; j < 4; ++j) {
            Bs[bg + j][bk]     = (bf16_t)b0[j];
            Bs[bg + 4 + j][bk] = (bf16_t)b1[j];
        }
        __syncthreads();

        bf16x8 af = *(const bf16x8*)(&As[w * 16 + (lane & 15)][(lane >> 4) * 8]);
        #pragma unroll
        for (int t = 0; t < 4; ++t) {
            bf16x8 bfv = *(const bf16x8*)(&Bs[t * 16 + (lane & 15)][(lane >> 4) * 8]);
            acc[t] = __builtin_amdgcn_mfma_f32_16x16x32_bf16(af, bfv, acc[t], 0, 0, 0);
        }
        __syncthreads();
    }

    const int qr = (lane >> 4) * 4;
    const int cn = lane & 15;
    #pragma unroll
    for (int t = 0; t < 4; ++t) {
        const int n = n0 + t * 16 + cn;
        const float bv = bias[n];
        float scale = 1.0f, shift = 0.0f;
        if (mode == 1) {
            float s = g[n] * rsqrtf(var[n] + EPS_BN);
            scale = s;
            shift = be[n] - mu[n] * s;
        }
        #pragma unroll
        for (int r = 0; r < 4; ++r) {
            const int m = m0 + w * 16 + qr + r;
            float val = acc[t][r] + bv;
            if (mode == 1) val = gelu_f(val * scale + shift);
            C[(size_t)m * NCOL + n] = val;
        }
    }
}

// ---------------------------------------------------------------------------
// GATv2 edge softmax + aggregate (single-pass online softmax).
// Grid (NNODES, BATCH), block 256 = 4 waves; wave w = head w.
// Lane split: eo = lane>>4 (4 edges in flight), cg = lane&15 (channel group,
// 4 channels each as float4). Per edge: 4-step shuffle reduce over 16 lanes
// (shared by 4 edges => 1 shuffle/edge). Online-softmax state per eo-chain,
// merged at the end with 2 butterfly steps (masks 16,32).
// ---------------------------------------------------------------------------
__global__ __launch_bounds__(256) void edge_kernel(
        const float* __restrict__ XL, const float* __restrict__ XR,
        const float* __restrict__ att, const float* __restrict__ bo,
        const int* __restrict__ noff, const int* __restrict__ csrc,
        float* __restrict__ Hout) {
    const int i    = blockIdx.x;
    const int b    = blockIdx.y;
    const int tid  = threadIdx.x;
    const int w    = tid >> 6;
    const int lane = tid & 63;
    const int eo   = lane >> 4;
    const int cg   = lane & 15;
    const int cbase = w * CDIM + cg * 4;
    const size_t base = (size_t)b * NNODES * HID;
    const float* xrow = XR + base + (size_t)i * HID + cbase;

    const f32x4 attv = *(const f32x4*)(att + cbase);
    const f32x4 xi   = *(const f32x4*)xrow;
    const int s0 = noff[i], s1 = noff[i + 1];

    float m = -1e30f, den = 0.f;
    f32x4 acc = (f32x4){0.f, 0.f, 0.f, 0.f};

    for (int e0 = s0; e0 < s1; e0 += 4) {
        const int e = e0 + eo;
        const bool valid = (e < s1);
        const int j = csrc[valid ? e : s0];
        const f32x4 xj = *(const f32x4*)(XL + base + (size_t)j * HID + cbase);
        float p = 0.f;
        #pragma unroll
        for (int q = 0; q < 4; ++q) {
            float v = xi[q] + xj[q];
            v = (v > 0.f) ? v : NEG_SLOPE * v;
            p += attv[q] * v;
        }
        p += __shfl_xor(p, 1, 64);
        p += __shfl_xor(p, 2, 64);
        p += __shfl_xor(p, 4, 64);
        p += __shfl_xor(p, 8, 64);
        if (valid) {
            const float mn = fmaxf(m, p);
            const float alpha = __expf(m - mn);
            const float we    = __expf(p - mn);
            den = den * alpha + we;
            #pragma unroll
            for (int q = 0; q < 4; ++q) acc[q] = acc[q] * alpha + we * xj[q];
            m = mn;
        }
    }

    // merge the 4 eo-chains (butterfly over lane bits 4,5)
    #pragma unroll
    for (int mask = 16; mask <= 32; mask <<= 1) {
        const float mo   = __shfl_xor(m, mask, 64);
        const float deno = __shfl_xor(den, mask, 64);
        f32x4 acco;
        #pragma unroll
        for (int q = 0; q < 4; ++q) acco[q] = __shfl_xor(acc[q], mask, 64);
        const float mm = fmaxf(m, mo);
        const float a1 = __expf(m - mm);
        const float a2 = __expf(mo - mm);
        den = den * a1 + deno * a2;
        #pragma unroll
        for (int q = 0; q < 4; ++q) acc[q] = acc[q] * a1 + acco[q] * a2;
        m = mm;
    }

    if (eo == 0) {
        f32x4 outv;
        #pragma unroll
        for (int q = 0; q < 4; ++q) {
            float o = (s1 > s0) ? acc[q] / (den + 1e-16f) : 0.f;
            o += bo[cbase + q];
            outv[q] = gelu_f(o);
        }
        *(f32x4*)(Hout + base + (size_t)i * HID + cbase) = outv;
    }
}

// ---------------------------------------------------------------------------
// Mean-pool over nodes: pooled[b][f] = mean_n H1[b][n][f]
// ---------------------------------------------------------------------------
__global__ __launch_bounds__(256) void pool_kernel(const float* __restrict__ H1,
                                                   float* __restrict__ pooled) {
    const int b = blockIdx.x, f = threadIdx.x;
    const float* p = H1 + (size_t)b * NNODES * HID + f;
    float s = 0.f;
    for (int n = 0; n < NNODES; ++n) s += p[(size_t)n * HID];
    pooled[b * HID + f] = s * (1.0f / (float)NNODES);
}

// ---------------------------------------------------------------------------
// Output proj: out = gelu(BN(pooled @ W2 + b2)). Tiny (64x256x256), fp32.
// ---------------------------------------------------------------------------
__global__ __launch_bounds__(256) void final_kernel(
        const float* __restrict__ pooled, const float* __restrict__ W2,
        const float* __restrict__ b2, const float* __restrict__ g2,
        const float* __restrict__ be2, const float* __restrict__ m2,
        const float* __restrict__ v2, float* __restrict__ out) {
    const int b = blockIdx.x, f = threadIdx.x;
    const float* pr = pooled + b * HID;
    float s = 0.f;
    for (int k = 0; k < HID; ++k) s += pr[k] * W2[(size_t)k * HID + f];
    s += b2[f];
    const float scale = g2[f] * rsqrtf(v2[f] + EPS_BN);
    s = (s - m2[f]) * scale + be2[f];
    out[b * HID + f] = gelu_f(s);
}

// ---------------------------------------------------------------------------
extern "C" void kernel_launch(void* const* d_in, const int* in_sizes, int n_in,
                              void* d_out, int out_size, void* d_ws, size_t ws_size,
                              hipStream_t stream) {
    const float* x    = (const float*)d_in[0];
    const int*   ei   = (const int*)d_in[1];
    const float* W1   = (const float*)d_in[2];
    const float* b1   = (const float*)d_in[3];
    const float* g1   = (const float*)d_in[4];
    const float* be1  = (const float*)d_in[5];
    const float* m1   = (const float*)d_in[6];
    const float* v1   = (const float*)d_in[7];
    const float* Wl0  = (const float*)d_in[8];
    const float* bl0  = (const float*)d_in[9];
    const float* Wr0  = (const float*)d_in[10];
    const float* br0  = (const float*)d_in[11];
    const float* att0 = (const float*)d_in[12];
    const float* bo0  = (const float*)d_in[13];
    const float* Wl1  = (const float*)d_in[14];
    const float* bl1  = (const float*)d_in[15];
    const float* Wr1  = (const float*)d_in[16];
    const float* br1  = (const float*)d_in[17];
    const float* att1 = (const float*)d_in[18];
    const float* bo1  = (const float*)d_in[19];
    const float* W2   = (const float*)d_in[20];
    const float* b2   = (const float*)d_in[21];
    const float* g2   = (const float*)d_in[22];
    const float* be2  = (const float*)d_in[23];
    const float* m2   = (const float*)d_in[24];
    const float* v2   = (const float*)d_in[25];

    char* ws = (char*)d_ws;
    const size_t SZ_H = (size_t)BATCH * NNODES * HID * sizeof(float);  // 16 MB
    int*   noff   = (int*)ws;                          //   2 KB (257 ints)
    int*   csrc   = (int*)(ws + 2048);                 //  32 KB
    float* H1buf  = (float*)(ws + 2048 + 32768);
    float* XL     = (float*)((char*)H1buf + SZ_H);
    float* XR     = (float*)((char*)XL + SZ_H);
    float* H2buf  = (float*)((char*)XR + SZ_H);
    float* pooled = (float*)((char*)H2buf + SZ_H);     //  64 KB

    const int M = BATCH * NNODES;                       // 16384
    dim3 ggrid(HID / BN, M / BM);                       // (4, 256)

    csr_kernel<<<1, 256, 0, stream>>>(ei, noff, csrc);

    // node_proj: H1buf = gelu(BN(x @ W1 + b1))
    gemm_kernel<<<ggrid, 256, 0, stream>>>(x, W1, H1buf, M, NNODES * 3,
                                           b1, g1, be1, m1, v1, 1);
    // GATv2 layer 0 projections
    gemm_kernel<<<ggrid, 256, 0, stream>>>(H1buf, Wl0, XL, M, HID,
                                           bl0, nullptr, nullptr, nullptr, nullptr, 0);
    gemm_kernel<<<ggrid, 256, 0, stream>>>(H1buf, Wr0, XR, M, HID,
                                           br0, nullptr, nullptr, nullptr, nullptr, 0);
    edge_kernel<<<dim3(NNODES, BATCH), 256, 0, stream>>>(XL, XR, att0, bo0,
                                                         noff, csrc, H2buf);
    // GATv2 layer 1 projections
    gemm_kernel<<<ggrid, 256, 0, stream>>>(H2buf, Wl1, XL, M, HID,
                                           bl1, nullptr, nullptr, nullptr, nullptr, 0);
    gemm_kernel<<<ggrid, 256, 0, stream>>>(H2buf, Wr1, XR, M, HID,
                                           br1, nullptr, nullptr, nullptr, nullptr, 0);
    edge_kernel<<<dim3(NNODES, BATCH), 256, 0, stream>>>(XL, XR, att1, bo1,
                                                         noff, csrc, H1buf);

    pool_kernel<<<BATCH, 256, 0, stream>>>(H1buf, pooled);
    final_kernel<<<BATCH, 256, 0, stream>>>(pooled, W2, b2, g2, be2, m2, v2,
                                            (float*)d_out);
}

// Round 4
// 370.303 us; speedup vs baseline: 2.4125x; 1.1558x over previous
//
#include <hip/hip_runtime.h>
#include <hip/hip_bf16.h>
#include <math.h>

// Problem constants (from reference)
#define BATCH   64
#define NNODES  256
#define HID     256
#define HEADS   4
#define CDIM    64
#define NEDGES  8192
#define NEG_SLOPE 0.2f
#define EPS_BN 1e-5f

typedef __bf16 bf16_t;
typedef __bf16 bf16x8 __attribute__((ext_vector_type(8)));
typedef float  f32x4  __attribute__((ext_vector_type(4)));

__device__ __forceinline__ float gelu_f(float x) {
    return 0.5f * x * (1.0f + erff(x * 0.70710678118654752440f));
}

// ---------------------------------------------------------------------------
// CSR build: one block, 256 threads. edge_index = [src[E], dst[E]] int32.
// ---------------------------------------------------------------------------
__global__ __launch_bounds__(256) void csr_kernel(const int* __restrict__ ei,
                                                  int* __restrict__ noff,
                                                  int* __restrict__ csrc) {
    __shared__ int cnt[NNODES];
    __shared__ int off_s[NNODES + 1];
    const int tid = threadIdx.x;
    cnt[tid] = 0;
    __syncthreads();
    for (int e = tid; e < NEDGES; e += 256) atomicAdd(&cnt[ei[NEDGES + e]], 1);
    __syncthreads();
    if (tid == 0) {
        int s = 0;
        for (int i = 0; i < NNODES; ++i) { off_s[i] = s; s += cnt[i]; }
        off_s[NNODES] = s;
    }
    __syncthreads();
    cnt[tid] = off_s[tid];
    noff[tid] = off_s[tid];
    if (tid == 0) noff[NNODES] = off_s[NNODES];
    __syncthreads();
    for (int e = tid; e < NEDGES; e += 256) {
        int d = ei[NEDGES + e];
        int p = atomicAdd(&cnt[d], 1);
        csrc[p] = ei[e];
    }
}

// ---------------------------------------------------------------------------
// Weight transpose + bf16 convert: Wt[n][k] = bf16(W[k][n]), N = 256 always.
// 5 matrices: W1 (K=768) + 4 lin weights (K=256). 32x32 LDS tiles.
// Grid.x = 24*8 + 4*64 = 448 blocks, block (32, 8).
// ---------------------------------------------------------------------------
__global__ __launch_bounds__(256) void trans_kernel(
        const float* __restrict__ W1, const float* __restrict__ Wa,
        const float* __restrict__ Wb, const float* __restrict__ Wc,
        const float* __restrict__ Wd,
        bf16_t* __restrict__ T1, bf16_t* __restrict__ Ta,
        bf16_t* __restrict__ Tb, bf16_t* __restrict__ Tc,
        bf16_t* __restrict__ Td) {
    __shared__ float tile[32][33];
    int bx = blockIdx.x;
    const float* in; bf16_t* out; int K, t;
    if (bx < 192) { in = W1; out = T1; K = 768; t = bx; }
    else {
        int r = bx - 192, mid = r >> 6; t = r & 63; K = 256;
        if (mid == 0) { in = Wa; out = Ta; }
        else if (mid == 1) { in = Wb; out = Tb; }
        else if (mid == 2) { in = Wc; out = Tc; }
        else { in = Wd; out = Td; }
    }
    const int kt = t >> 3, nt = t & 7;
    const int k0 = kt * 32, n0 = nt * 32;
    const int x = threadIdx.x, y = threadIdx.y;
    #pragma unroll
    for (int j = 0; j < 4; ++j)
        tile[y + j * 8][x] = in[(size_t)(k0 + y + j * 8) * 256 + n0 + x];
    __syncthreads();
    #pragma unroll
    for (int j = 0; j < 4; ++j)
        out[(size_t)(n0 + y + j * 8) * K + k0 + x] = (bf16_t)tile[x][y + j * 8];
}

// ---------------------------------------------------------------------------
// MFMA bf16 GEMM: C[M x 256] = A[M x K] @ B[K x 256], B given pre-transposed
// bf16 Bt[n][k]. Tile 128(M) x 64(N), BK=32, 256 threads = 4 waves (2x2),
// each wave 64x32 out (4 m-frags x 2 n-frags). 8 MFMA : 6 ds_read_b128.
// A_F32: A is fp32 (else bf16). DUAL: grid.x 0..3 -> C0(bf16,bias0),
// 4..7 -> C1(f32,bias1). EPI_BN: C0 = gelu(BN(acc+bias)).
// ---------------------------------------------------------------------------
#define GSTR 56   // LDS row stride (112 B: 16B-aligned, 2-way banks on frag reads)

template<int A_F32, int DUAL, int EPI_BN>
__global__ __launch_bounds__(256) void gemm_kernel(
        const void* __restrict__ Ap,
        const bf16_t* __restrict__ Bt0, const bf16_t* __restrict__ Bt1,
        void* __restrict__ C0p, void* __restrict__ C1p, int K,
        const float* __restrict__ bias0, const float* __restrict__ bias1,
        const float* __restrict__ g, const float* __restrict__ be,
        const float* __restrict__ mu, const float* __restrict__ var) {
    __shared__ bf16_t As[128][GSTR];
    __shared__ bf16_t Bs[64][GSTR];
    const int tid  = threadIdx.x;
    const int lane = tid & 63;
    const int wv   = tid >> 6;
    const int wm   = wv >> 1, wn = wv & 1;
    const int mblk = blockIdx.y * 128;
    const int nt   = blockIdx.x;
    const bool second = DUAL && (nt >= 4);
    const bf16_t* Bt = second ? Bt1 : Bt0;
    const int n0 = (second ? (nt - 4) : nt) * 64;

    f32x4 acc[8];
    #pragma unroll
    for (int i = 0; i < 8; ++i) acc[i] = (f32x4){0.f, 0.f, 0.f, 0.f};

    const int arow = tid >> 1, akh = (tid & 1) * 16;
    const int brow = tid >> 2, bkh = (tid & 3) * 8;
    const int fm = lane & 15, kc = (lane >> 4) * 8;

    for (int k0 = 0; k0 < K; k0 += 32) {
        if (A_F32) {
            const float* ap = (const float*)Ap + (size_t)(mblk + arow) * K + k0 + akh;
            f32x4 a0 = *(const f32x4*)ap;
            f32x4 a1 = *(const f32x4*)(ap + 4);
            f32x4 a2 = *(const f32x4*)(ap + 8);
            f32x4 a3 = *(const f32x4*)(ap + 12);
            bf16x8 v0, v1;
            #pragma unroll
            for (int j = 0; j < 4; ++j) {
                v0[j] = (bf16_t)a0[j]; v0[4 + j] = (bf16_t)a1[j];
                v1[j] = (bf16_t)a2[j]; v1[4 + j] = (bf16_t)a3[j];
            }
            *(bf16x8*)(&As[arow][akh])     = v0;
            *(bf16x8*)(&As[arow][akh + 8]) = v1;
        } else {
            const bf16_t* ap = (const bf16_t*)Ap + (size_t)(mblk + arow) * K + k0 + akh;
            *(bf16x8*)(&As[arow][akh])     = *(const bf16x8*)ap;
            *(bf16x8*)(&As[arow][akh + 8]) = *(const bf16x8*)(ap + 8);
        }
        *(bf16x8*)(&Bs[brow][bkh]) =
            *(const bf16x8*)(Bt + (size_t)(n0 + brow) * K + k0 + bkh);
        __syncthreads();

        bf16x8 af[4], bf[2];
        #pragma unroll
        for (int f = 0; f < 4; ++f)
            af[f] = *(const bf16x8*)(&As[wm * 64 + f * 16 + fm][kc]);
        #pragma unroll
        for (int t = 0; t < 2; ++t)
            bf[t] = *(const bf16x8*)(&Bs[wn * 32 + t * 16 + fm][kc]);
        #pragma unroll
        for (int f = 0; f < 4; ++f)
            #pragma unroll
            for (int t = 0; t < 2; ++t)
                acc[f * 2 + t] = __builtin_amdgcn_mfma_f32_16x16x32_bf16(
                    af[f], bf[t], acc[f * 2 + t], 0, 0, 0);
        __syncthreads();
    }

    const int quad = lane >> 4, cn = lane & 15;
    #pragma unroll
    for (int t = 0; t < 2; ++t) {
        const int n = n0 + wn * 32 + t * 16 + cn;
        const float bv = second ? bias1[n] : bias0[n];
        float scale = 1.0f, shift = 0.0f;
        if (EPI_BN) {
            float s = g[n] * rsqrtf(var[n] + EPS_BN);
            scale = s;
            shift = be[n] - mu[n] * s;
        }
        #pragma unroll
        for (int f = 0; f < 4; ++f) {
            #pragma unroll
            for (int r = 0; r < 4; ++r) {
                const int m = mblk + wm * 64 + f * 16 + quad * 4 + r;
                float val = acc[f * 2 + t][r] + bv;
                if (EPI_BN) val = gelu_f(val * scale + shift);
                if (second) ((float*)C1p)[(size_t)m * 256 + n] = val;
                else        ((bf16_t*)C0p)[(size_t)m * 256 + n] = (bf16_t)val;
            }
        }
    }
}

// ---------------------------------------------------------------------------
// GATv2 edge softmax + aggregate (single-pass online softmax, prefetched).
// Grid (NNODES, BATCH), block 256 = 4 waves = 4 heads.
// Lane split: eo = lane>>3 (8 edges in flight), cg = lane&7 (8 ch each).
// lrelu(z) = 0.6z + 0.4|z|  ->  p += 0.6att*z; p += 0.4att*|z| (abs is free).
// 3-step shuffle reduce over 8 lanes; 3-step chain merge at end.
// XL is bf16; XR fp32. OUT_F32 selects output dtype.
// ---------------------------------------------------------------------------
template<int OUT_F32>
__global__ __launch_bounds__(256) void edge_kernel(
        const bf16_t* __restrict__ XL, const float* __restrict__ XR,
        const float* __restrict__ att, const float* __restrict__ bo,
        const int* __restrict__ noff, const int* __restrict__ csrc,
        void* __restrict__ Hout) {
    const int i    = blockIdx.x;
    const int b    = blockIdx.y;
    const int tid  = threadIdx.x;
    const int w    = tid >> 6;
    const int lane = tid & 63;
    const int eo   = lane >> 3;
    const int cg   = lane & 7;
    const int cbase = w * CDIM + cg * 8;
    const size_t rowbase = (size_t)b * NNODES;

    float a6[8], a4[8], xi[8];
    {
        const float* ar = att + cbase;
        const float* xr = XR + (rowbase + i) * HID + cbase;
        #pragma unroll
        for (int q = 0; q < 8; ++q) {
            float a = ar[q];
            a6[q] = 0.6f * a; a4[q] = 0.4f * a;
            xi[q] = xr[q];
        }
    }
    const int s0 = noff[i], s1 = noff[i + 1];

    float m = -1e30f, den = 0.f;
    float acc[8];
    #pragma unroll
    for (int q = 0; q < 8; ++q) acc[q] = 0.f;

    const bf16_t* XLb = XL + rowbase * HID + cbase;

    int e = s0 + eo;
    int jc = csrc[e < s1 ? e : s0];
    bf16x8 xjp = *(const bf16x8*)(XLb + (size_t)jc * HID);

    for (int e0 = s0; e0 < s1; e0 += 8) {
        // prefetch next (clamped index keeps address valid)
        const int en = e0 + 8 + eo;
        const int jn = csrc[en < s1 ? en : s0];
        const bf16x8 xjn = *(const bf16x8*)(XLb + (size_t)jn * HID);

        float xjf[8];
        #pragma unroll
        for (int q = 0; q < 8; ++q) xjf[q] = (float)xjp[q];
        float p = 0.f;
        #pragma unroll
        for (int q = 0; q < 8; ++q) {
            const float z = xi[q] + xjf[q];
            p = fmaf(a6[q], z, p);
            p = fmaf(a4[q], __builtin_fabsf(z), p);
        }
        p += __shfl_xor(p, 1, 64);
        p += __shfl_xor(p, 2, 64);
        p += __shfl_xor(p, 4, 64);

        const float vf = ((e0 + eo) < s1) ? 1.f : 0.f;
        const float mn = fmaxf(m, p);
        const float alpha = __expf(m - mn);
        const float we = __expf(p - mn) * vf;
        den = den * alpha + we;
        #pragma unroll
        for (int q = 0; q < 8; ++q) acc[q] = acc[q] * alpha + we * xjf[q];
        m = mn;
        xjp = xjn;
    }

    // merge the 8 eo-chains (butterfly over lane bits 3,4,5)
    #pragma unroll
    for (int mask = 8; mask <= 32; mask <<= 1) {
        const float mo   = __shfl_xor(m, mask, 64);
        const float deno = __shfl_xor(den, mask, 64);
        float acco[8];
        #pragma unroll
        for (int q = 0; q < 8; ++q) acco[q] = __shfl_xor(acc[q], mask, 64);
        const float mm = fmaxf(m, mo);
        const float g1 = __expf(m - mm);
        const float g2 = __expf(mo - mm);
        den = den * g1 + deno * g2;
        #pragma unroll
        for (int q = 0; q < 8; ++q) acc[q] = acc[q] * g1 + acco[q] * g2;
        m = mm;
    }

    if (eo == 0) {
        const float* bor = bo + cbase;
        if (OUT_F32) {
            float* op = (float*)Hout + (rowbase + i) * HID + cbase;
            #pragma unroll
            for (int q = 0; q < 8; ++q) {
                float o = (s1 > s0) ? acc[q] / (den + 1e-16f) : 0.f;
                op[q] = gelu_f(o + bor[q]);
            }
        } else {
            bf16x8 ov;
            #pragma unroll
            for (int q = 0; q < 8; ++q) {
                float o = (s1 > s0) ? acc[q] / (den + 1e-16f) : 0.f;
                ov[q] = (bf16_t)gelu_f(o + bor[q]);
            }
            *(bf16x8*)((bf16_t*)Hout + (rowbase + i) * HID + cbase) = ov;
        }
    }
}

// ---------------------------------------------------------------------------
// Mean-pool partials: grid (B, 4); block (b,c) sums nodes [c*64, c*64+64).
// ---------------------------------------------------------------------------
__global__ __launch_bounds__(256) void pool_kernel(const float* __restrict__ H1,
                                                   float* __restrict__ P) {
    const int b = blockIdx.x, c = blockIdx.y, f = threadIdx.x;
    const float* p = H1 + ((size_t)b * NNODES + c * 64) * HID + f;
    float s = 0.f;
    for (int n = 0; n < 64; ++n) s += p[(size_t)n * HID];
    P[((size_t)b * 4 + c) * HID + f] = s;
}

// ---------------------------------------------------------------------------
// Output proj: out = gelu(BN(pooled @ W2 + b2)). pooled from 4 partials.
// ---------------------------------------------------------------------------
__global__ __launch_bounds__(256) void final_kernel(
        const float* __restrict__ P, const float* __restrict__ W2,
        const float* __restrict__ b2, const float* __restrict__ g2,
        const float* __restrict__ be2, const float* __restrict__ m2,
        const float* __restrict__ v2, float* __restrict__ out) {
    __shared__ float pl[HID];
    const int b = blockIdx.x, f = threadIdx.x;
    float s4 = 0.f;
    #pragma unroll
    for (int c = 0; c < 4; ++c) s4 += P[((size_t)b * 4 + c) * HID + f];
    pl[f] = s4 * (1.0f / (float)NNODES);
    __syncthreads();
    float s = 0.f;
    for (int k = 0; k < HID; ++k) s += pl[k] * W2[(size_t)k * HID + f];
    s += b2[f];
    const float scale = g2[f] * rsqrtf(v2[f] + EPS_BN);
    s = (s - m2[f]) * scale + be2[f];
    out[b * HID + f] = gelu_f(s);
}

// ---------------------------------------------------------------------------
extern "C" void kernel_launch(void* const* d_in, const int* in_sizes, int n_in,
                              void* d_out, int out_size, void* d_ws, size_t ws_size,
                              hipStream_t stream) {
    const float* x    = (const float*)d_in[0];
    const int*   ei   = (const int*)d_in[1];
    const float* W1   = (const float*)d_in[2];
    const float* b1   = (const float*)d_in[3];
    const float* g1   = (const float*)d_in[4];
    const float* be1  = (const float*)d_in[5];
    const float* m1   = (const float*)d_in[6];
    const float* v1   = (const float*)d_in[7];
    const float* Wl0  = (const float*)d_in[8];
    const float* bl0  = (const float*)d_in[9];
    const float* Wr0  = (const float*)d_in[10];
    const float* br0  = (const float*)d_in[11];
    const float* att0 = (const float*)d_in[12];
    const float* bo0  = (const float*)d_in[13];
    const float* Wl1  = (const float*)d_in[14];
    const float* bl1  = (const float*)d_in[15];
    const float* Wr1  = (const float*)d_in[16];
    const float* br1  = (const float*)d_in[17];
    const float* att1 = (const float*)d_in[18];
    const float* bo1  = (const float*)d_in[19];
    const float* W2   = (const float*)d_in[20];
    const float* b2   = (const float*)d_in[21];
    const float* g2   = (const float*)d_in[22];
    const float* be2  = (const float*)d_in[23];
    const float* m2   = (const float*)d_in[24];
    const float* v2   = (const float*)d_in[25];

    char* ws = (char*)d_ws;
    const int M = BATCH * NNODES;                        // 16384
    const size_t SZ_BF = (size_t)M * HID * sizeof(bf16_t);   // 8 MB
    const size_t SZ_F  = (size_t)M * HID * sizeof(float);    // 16 MB

    int*    noff = (int*)ws;                ws += 2048;
    int*    csrc = (int*)ws;                ws += 32768;
    bf16_t* W1t  = (bf16_t*)ws;             ws += 256 * 768 * 2;
    bf16_t* Wl0t = (bf16_t*)ws;             ws += 256 * 256 * 2;
    bf16_t* Wr0t = (bf16_t*)ws;             ws += 256 * 256 * 2;
    bf16_t* Wl1t = (bf16_t*)ws;             ws += 256 * 256 * 2;
    bf16_t* Wr1t = (bf16_t*)ws;             ws += 256 * 256 * 2;
    bf16_t* H    = (bf16_t*)ws;             ws += SZ_BF;   // node_proj out (bf16)
    bf16_t* H2   = (bf16_t*)ws;             ws += SZ_BF;   // edge0 out (bf16)
    bf16_t* XL   = (bf16_t*)ws;             ws += SZ_BF;   // lin_l out (bf16)
    float*  XR   = (float*)ws;              ws += SZ_F;    // lin_r out (f32)
    float*  H1f  = (float*)ws;              ws += SZ_F;    // edge1 out (f32)
    float*  P    = (float*)ws;              ws += BATCH * 4 * HID * 4;

    csr_kernel<<<1, 256, 0, stream>>>(ei, noff, csrc);
    trans_kernel<<<448, dim3(32, 8), 0, stream>>>(W1, Wl0, Wr0, Wl1, Wr1,
                                                  W1t, Wl0t, Wr0t, Wl1t, Wr1t);

    // node_proj: H = gelu(BN(x @ W1 + b1))   [A fp32, K=768]
    gemm_kernel<1, 0, 1><<<dim3(4, 128), 256, 0, stream>>>(
        x, W1t, nullptr, H, nullptr, 768, b1, nullptr, g1, be1, m1, v1);

    // layer 0: XL = H@Wl0+bl0 (bf16), XR = H@Wr0+br0 (f32)
    gemm_kernel<0, 1, 0><<<dim3(8, 128), 256, 0, stream>>>(
        H, Wl0t, Wr0t, XL, XR, 256, bl0, br0, nullptr, nullptr, nullptr, nullptr);
    edge_kernel<0><<<dim3(NNODES, BATCH), 256, 0, stream>>>(
        XL, XR, att0, bo0, noff, csrc, H2);

    // layer 1
    gemm_kernel<0, 1, 0><<<dim3(8, 128), 256, 0, stream>>>(
        H2, Wl1t, Wr1t, XL, XR, 256, bl1, br1, nullptr, nullptr, nullptr, nullptr);
    edge_kernel<1><<<dim3(NNODES, BATCH), 256, 0, stream>>>(
        XL, XR, att1, bo1, noff, csrc, H1f);

    pool_kernel<<<dim3(BATCH, 4), 256, 0, stream>>>(H1f, P);
    final_kernel<<<BATCH, 256, 0, stream>>>(P, W2, b2, g2, be2, m2, v2,
                                            (float*)d_out);
}

// Round 5
// 318.429 us; speedup vs baseline: 2.8055x; 1.1629x over previous
//
#include <hip/hip_runtime.h>
#include <hip/hip_bf16.h>
#include <math.h>

// Problem constants (from reference)
#define BATCH   64
#define NNODES  256
#define HID     256
#define HEADS   4
#define CDIM    64
#define NEDGES  8192
#define NEG_SLOPE 0.2f
#define EPS_BN 1e-5f

// All intermediate activations use NODE-MAJOR layout: row = node*64 + batch.

typedef __bf16 bf16_t;
typedef __bf16 bf16x8 __attribute__((ext_vector_type(8)));
typedef float  f32x4  __attribute__((ext_vector_type(4)));

__device__ __forceinline__ float gelu_f(float x) {
    return 0.5f * x * (1.0f + erff(x * 0.70710678118654752440f));
}

// ---------------------------------------------------------------------------
// CSR build: one block, 256 threads. edge_index = [src[E], dst[E]] int32.
// ---------------------------------------------------------------------------
__global__ __launch_bounds__(256) void csr_kernel(const int* __restrict__ ei,
                                                  int* __restrict__ noff,
                                                  int* __restrict__ csrc) {
    __shared__ int cnt[NNODES];
    __shared__ int off_s[NNODES + 1];
    const int tid = threadIdx.x;
    cnt[tid] = 0;
    __syncthreads();
    for (int e = tid; e < NEDGES; e += 256) atomicAdd(&cnt[ei[NEDGES + e]], 1);
    __syncthreads();
    if (tid == 0) {
        int s = 0;
        for (int i = 0; i < NNODES; ++i) { off_s[i] = s; s += cnt[i]; }
        off_s[NNODES] = s;
    }
    __syncthreads();
    cnt[tid] = off_s[tid];
    noff[tid] = off_s[tid];
    if (tid == 0) noff[NNODES] = off_s[NNODES];
    __syncthreads();
    for (int e = tid; e < NEDGES; e += 256) {
        int d = ei[NEDGES + e];
        int p = atomicAdd(&cnt[d], 1);
        csrc[p] = ei[e];
    }
}

// ---------------------------------------------------------------------------
// Weight transpose + bf16 convert: Wt[n][k] = bf16(W[k][n]), N = 256 always.
// ---------------------------------------------------------------------------
__global__ __launch_bounds__(256) void trans_kernel(
        const float* __restrict__ W1, const float* __restrict__ Wa,
        const float* __restrict__ Wb, const float* __restrict__ Wc,
        const float* __restrict__ Wd,
        bf16_t* __restrict__ T1, bf16_t* __restrict__ Ta,
        bf16_t* __restrict__ Tb, bf16_t* __restrict__ Tc,
        bf16_t* __restrict__ Td) {
    __shared__ float tile[32][33];
    int bx = blockIdx.x;
    const float* in; bf16_t* out; int K, t;
    if (bx < 192) { in = W1; out = T1; K = 768; t = bx; }
    else {
        int r = bx - 192, mid = r >> 6; t = r & 63; K = 256;
        if (mid == 0) { in = Wa; out = Ta; }
        else if (mid == 1) { in = Wb; out = Tb; }
        else if (mid == 2) { in = Wc; out = Tc; }
        else { in = Wd; out = Td; }
    }
    const int kt = t >> 3, nt = t & 7;
    const int k0 = kt * 32, n0 = nt * 32;
    const int x = threadIdx.x, y = threadIdx.y;
    #pragma unroll
    for (int j = 0; j < 4; ++j)
        tile[y + j * 8][x] = in[(size_t)(k0 + y + j * 8) * 256 + n0 + x];
    __syncthreads();
    #pragma unroll
    for (int j = 0; j < 4; ++j)
        out[(size_t)(n0 + y + j * 8) * K + k0 + x] = (bf16_t)tile[x][y + j * 8];
}

// ---------------------------------------------------------------------------
// MFMA bf16 GEMM: C[M x 256] = A[M x K] @ B[K x 256], B pre-transposed bf16.
// Tile 128(M) x 64(N), BK=32, 4 waves (2x2). PERM: A row = (r%64)*256+r/64
// (batch-major input -> node-major output, node_proj only).
// DUAL: grid.x 0..3 -> C0(bf16,bias0), 4..7 -> C1(f32,bias1).
// ---------------------------------------------------------------------------
#define GSTR 56

template<int A_F32, int DUAL, int EPI_BN, int PERM>
__global__ __launch_bounds__(256) void gemm_kernel(
        const void* __restrict__ Ap,
        const bf16_t* __restrict__ Bt0, const bf16_t* __restrict__ Bt1,
        void* __restrict__ C0p, void* __restrict__ C1p, int K,
        const float* __restrict__ bias0, const float* __restrict__ bias1,
        const float* __restrict__ g, const float* __restrict__ be,
        const float* __restrict__ mu, const float* __restrict__ var) {
    __shared__ bf16_t As[128][GSTR];
    __shared__ bf16_t Bs[64][GSTR];
    const int tid  = threadIdx.x;
    const int lane = tid & 63;
    const int wv   = tid >> 6;
    const int wm   = wv >> 1, wn = wv & 1;
    const int mblk = blockIdx.y * 128;
    const int nt   = blockIdx.x;
    const bool second = DUAL && (nt >= 4);
    const bf16_t* Bt = second ? Bt1 : Bt0;
    const int n0 = (second ? (nt - 4) : nt) * 64;

    f32x4 acc[8];
    #pragma unroll
    for (int i = 0; i < 8; ++i) acc[i] = (f32x4){0.f, 0.f, 0.f, 0.f};

    const int arow = tid >> 1, akh = (tid & 1) * 16;
    const int gr   = mblk + arow;                       // output row (node-major)
    const int arr  = PERM ? ((gr & 63) * 256 + (gr >> 6)) : gr;  // A source row
    const int brow = tid >> 2, bkh = (tid & 3) * 8;
    const int fm = lane & 15, kc = (lane >> 4) * 8;

    for (int k0 = 0; k0 < K; k0 += 32) {
        if (A_F32) {
            const float* ap = (const float*)Ap + (size_t)arr * K + k0 + akh;
            f32x4 a0 = *(const f32x4*)ap;
            f32x4 a1 = *(const f32x4*)(ap + 4);
            f32x4 a2 = *(const f32x4*)(ap + 8);
            f32x4 a3 = *(const f32x4*)(ap + 12);
            bf16x8 v0, v1;
            #pragma unroll
            for (int j = 0; j < 4; ++j) {
                v0[j] = (bf16_t)a0[j]; v0[4 + j] = (bf16_t)a1[j];
                v1[j] = (bf16_t)a2[j]; v1[4 + j] = (bf16_t)a3[j];
            }
            *(bf16x8*)(&As[arow][akh])     = v0;
            *(bf16x8*)(&As[arow][akh + 8]) = v1;
        } else {
            const bf16_t* ap = (const bf16_t*)Ap + (size_t)arr * K + k0 + akh;
            *(bf16x8*)(&As[arow][akh])     = *(const bf16x8*)ap;
            *(bf16x8*)(&As[arow][akh + 8]) = *(const bf16x8*)(ap + 8);
        }
        *(bf16x8*)(&Bs[brow][bkh]) =
            *(const bf16x8*)(Bt + (size_t)(n0 + brow) * K + k0 + bkh);
        __syncthreads();

        bf16x8 af[4], bf[2];
        #pragma unroll
        for (int f = 0; f < 4; ++f)
            af[f] = *(const bf16x8*)(&As[wm * 64 + f * 16 + fm][kc]);
        #pragma unroll
        for (int t = 0; t < 2; ++t)
            bf[t] = *(const bf16x8*)(&Bs[wn * 32 + t * 16 + fm][kc]);
        #pragma unroll
        for (int f = 0; f < 4; ++f)
            #pragma unroll
            for (int t = 0; t < 2; ++t)
                acc[f * 2 + t] = __builtin_amdgcn_mfma_f32_16x16x32_bf16(
                    af[f], bf[t], acc[f * 2 + t], 0, 0, 0);
        __syncthreads();
    }

    const int quad = lane >> 4, cn = lane & 15;
    #pragma unroll
    for (int t = 0; t < 2; ++t) {
        const int n = n0 + wn * 32 + t * 16 + cn;
        const float bv = second ? bias1[n] : bias0[n];
        float scale = 1.0f, shift = 0.0f;
        if (EPI_BN) {
            float s = g[n] * rsqrtf(var[n] + EPS_BN);
            scale = s;
            shift = be[n] - mu[n] * s;
        }
        #pragma unroll
        for (int f = 0; f < 4; ++f) {
            #pragma unroll
            for (int r = 0; r < 4; ++r) {
                const int m = mblk + wm * 64 + f * 16 + quad * 4 + r;
                float val = acc[f * 2 + t][r] + bv;
                if (EPI_BN) val = gelu_f(val * scale + shift);
                if (second) ((float*)C1p)[(size_t)m * 256 + n] = val;
                else        ((bf16_t*)C0p)[(size_t)m * 256 + n] = (bf16_t)val;
            }
        }
    }
}

// ---------------------------------------------------------------------------
// GATv2 edge softmax + aggregate, node-major batched.
// Grid (NNODES, 8): block = (node i, 8-batch group). 4 waves = 4 heads.
// Lane: bg = lane>>3 (batch), cg = lane&7 (8 channels). Loop over the node's
// exact neighbor list (uniform e -> scalar csrc loads, no masks). All lanes
// of a bg-group share identical (m,den) after the 3-shuffle reduce -> no
// final merge. lrelu(z) = 0.6z + 0.4|z|.
// ---------------------------------------------------------------------------
template<int OUT_F32>
__global__ __launch_bounds__(256) void edge_kernel(
        const bf16_t* __restrict__ XL, const float* __restrict__ XR,
        const float* __restrict__ att, const float* __restrict__ bo,
        const int* __restrict__ noff, const int* __restrict__ csrc,
        void* __restrict__ Hout) {
    const int i    = blockIdx.x;
    const int tid  = threadIdx.x;
    const int w    = tid >> 6;
    const int lane = tid & 63;
    const int bg   = lane >> 3;
    const int cg   = lane & 7;
    const int b    = blockIdx.y * 8 + bg;
    const int cbase = w * CDIM + cg * 8;
    const size_t orow = ((size_t)i * BATCH + b) * HID + cbase;

    float a6[8], a4[8], xi[8];
    {
        const float* ar = att + cbase;
        const float* xr = XR + orow;
        #pragma unroll
        for (int q = 0; q < 8; ++q) {
            float a = ar[q];
            a6[q] = 0.6f * a; a4[q] = 0.4f * a;
            xi[q] = xr[q];
        }
    }
    const int s0 = noff[i], s1 = noff[i + 1];

    float m = -1e30f, den = 0.f;
    float acc[8];
    #pragma unroll
    for (int q = 0; q < 8; ++q) acc[q] = 0.f;

    const bf16_t* XLb = XL + (size_t)b * HID + cbase;

    int jc = csrc[s0 < s1 ? s0 : 0];
    bf16x8 xjp = *(const bf16x8*)(XLb + (size_t)jc * (BATCH * HID));

    for (int e = s0; e < s1; ++e) {
        const int en = e + 1;
        const int jn = csrc[en < s1 ? en : s0];
        const bf16x8 xjn = *(const bf16x8*)(XLb + (size_t)jn * (BATCH * HID));

        float xjf[8];
        #pragma unroll
        for (int q = 0; q < 8; ++q) xjf[q] = (float)xjp[q];
        float p = 0.f;
        #pragma unroll
        for (int q = 0; q < 8; ++q) {
            const float z = xi[q] + xjf[q];
            p = fmaf(a6[q], z, p);
            p = fmaf(a4[q], __builtin_fabsf(z), p);
        }
        p += __shfl_xor(p, 1, 64);
        p += __shfl_xor(p, 2, 64);
        p += __shfl_xor(p, 4, 64);

        const float mn = fmaxf(m, p);
        const float alpha = __expf(m - mn);
        const float we = __expf(p - mn);
        den = den * alpha + we;
        #pragma unroll
        for (int q = 0; q < 8; ++q) acc[q] = fmaf(acc[q], alpha, we * xjf[q]);
        m = mn;
        xjp = xjn;
    }

    const float inv = 1.0f / (den + 1e-16f);
    const float* bor = bo + cbase;
    if (OUT_F32) {
        float* op = (float*)Hout + orow;
        #pragma unroll
        for (int q = 0; q < 8; ++q)
            op[q] = gelu_f(acc[q] * inv + bor[q]);
    } else {
        bf16x8 ov;
        #pragma unroll
        for (int q = 0; q < 8; ++q)
            ov[q] = (bf16_t)gelu_f(acc[q] * inv + bor[q]);
        *(bf16x8*)((bf16_t*)Hout + orow) = ov;
    }
}

// ---------------------------------------------------------------------------
// Mean-pool partials (node-major input): block (b,c) sums nodes [c*64,c*64+64).
// ---------------------------------------------------------------------------
__global__ __launch_bounds__(256) void pool_kernel(const float* __restrict__ H1,
                                                   float* __restrict__ P) {
    const int b = blockIdx.x, c = blockIdx.y, f = threadIdx.x;
    float s = 0.f;
    for (int n = 0; n < 64; ++n)
        s += H1[((size_t)(c * 64 + n) * BATCH + b) * HID + f];
    P[((size_t)b * 4 + c) * HID + f] = s;
}

// ---------------------------------------------------------------------------
// Output proj: out = gelu(BN(pooled @ W2 + b2)). pooled from 4 partials.
// ---------------------------------------------------------------------------
__global__ __launch_bounds__(256) void final_kernel(
        const float* __restrict__ P, const float* __restrict__ W2,
        const float* __restrict__ b2, const float* __restrict__ g2,
        const float* __restrict__ be2, const float* __restrict__ m2,
        const float* __restrict__ v2, float* __restrict__ out) {
    __shared__ float pl[HID];
    const int b = blockIdx.x, f = threadIdx.x;
    float s4 = 0.f;
    #pragma unroll
    for (int c = 0; c < 4; ++c) s4 += P[((size_t)b * 4 + c) * HID + f];
    pl[f] = s4 * (1.0f / (float)NNODES);
    __syncthreads();
    float s = 0.f;
    for (int k = 0; k < HID; ++k) s += pl[k] * W2[(size_t)k * HID + f];
    s += b2[f];
    const float scale = g2[f] * rsqrtf(v2[f] + EPS_BN);
    s = (s - m2[f]) * scale + be2[f];
    out[b * HID + f] = gelu_f(s);
}

// ---------------------------------------------------------------------------
extern "C" void kernel_launch(void* const* d_in, const int* in_sizes, int n_in,
                              void* d_out, int out_size, void* d_ws, size_t ws_size,
                              hipStream_t stream) {
    const float* x    = (const float*)d_in[0];
    const int*   ei   = (const int*)d_in[1];
    const float* W1   = (const float*)d_in[2];
    const float* b1   = (const float*)d_in[3];
    const float* g1   = (const float*)d_in[4];
    const float* be1  = (const float*)d_in[5];
    const float* m1   = (const float*)d_in[6];
    const float* v1   = (const float*)d_in[7];
    const float* Wl0  = (const float*)d_in[8];
    const float* bl0  = (const float*)d_in[9];
    const float* Wr0  = (const float*)d_in[10];
    const float* br0  = (const float*)d_in[11];
    const float* att0 = (const float*)d_in[12];
    const float* bo0  = (const float*)d_in[13];
    const float* Wl1  = (const float*)d_in[14];
    const float* bl1  = (const float*)d_in[15];
    const float* Wr1  = (const float*)d_in[16];
    const float* br1  = (const float*)d_in[17];
    const float* att1 = (const float*)d_in[18];
    const float* bo1  = (const float*)d_in[19];
    const float* W2   = (const float*)d_in[20];
    const float* b2   = (const float*)d_in[21];
    const float* g2   = (const float*)d_in[22];
    const float* be2  = (const float*)d_in[23];
    const float* m2   = (const float*)d_in[24];
    const float* v2   = (const float*)d_in[25];

    char* ws = (char*)d_ws;
    const int M = BATCH * NNODES;                        // 16384
    const size_t SZ_BF = (size_t)M * HID * sizeof(bf16_t);   // 8 MB
    const size_t SZ_F  = (size_t)M * HID * sizeof(float);    // 16 MB

    int*    noff = (int*)ws;                ws += 2048;
    int*    csrc = (int*)ws;                ws += 32768;
    bf16_t* W1t  = (bf16_t*)ws;             ws += 256 * 768 * 2;
    bf16_t* Wl0t = (bf16_t*)ws;             ws += 256 * 256 * 2;
    bf16_t* Wr0t = (bf16_t*)ws;             ws += 256 * 256 * 2;
    bf16_t* Wl1t = (bf16_t*)ws;             ws += 256 * 256 * 2;
    bf16_t* Wr1t = (bf16_t*)ws;             ws += 256 * 256 * 2;
    bf16_t* H    = (bf16_t*)ws;             ws += SZ_BF;   // node_proj out (bf16, node-major)
    bf16_t* H2   = (bf16_t*)ws;             ws += SZ_BF;   // edge0 out (bf16, node-major)
    bf16_t* XL   = (bf16_t*)ws;             ws += SZ_BF;   // lin_l out (bf16, node-major)
    float*  XR   = (float*)ws;              ws += SZ_F;    // lin_r out (f32, node-major)
    float*  H1f  = (float*)ws;              ws += SZ_F;    // edge1 out (f32, node-major)
    float*  P    = (float*)ws;              ws += BATCH * 4 * HID * 4;

    csr_kernel<<<1, 256, 0, stream>>>(ei, noff, csrc);
    trans_kernel<<<448, dim3(32, 8), 0, stream>>>(W1, Wl0, Wr0, Wl1, Wr1,
                                                  W1t, Wl0t, Wr0t, Wl1t, Wr1t);

    // node_proj: H = gelu(BN(x @ W1 + b1)), batch-major A -> node-major C
    gemm_kernel<1, 0, 1, 1><<<dim3(4, 128), 256, 0, stream>>>(
        x, W1t, nullptr, H, nullptr, 768, b1, nullptr, g1, be1, m1, v1);

    // layer 0: XL = H@Wl0+bl0 (bf16), XR = H@Wr0+br0 (f32)
    gemm_kernel<0, 1, 0, 0><<<dim3(8, 128), 256, 0, stream>>>(
        H, Wl0t, Wr0t, XL, XR, 256, bl0, br0, nullptr, nullptr, nullptr, nullptr);
    edge_kernel<0><<<dim3(NNODES, 8), 256, 0, stream>>>(
        XL, XR, att0, bo0, noff, csrc, H2);

    // layer 1
    gemm_kernel<0, 1, 0, 0><<<dim3(8, 128), 256, 0, stream>>>(
        H2, Wl1t, Wr1t, XL, XR, 256, bl1, br1, nullptr, nullptr, nullptr, nullptr);
    edge_kernel<1><<<dim3(NNODES, 8), 256, 0, stream>>>(
        XL, XR, att1, bo1, noff, csrc, H1f);

    pool_kernel<<<dim3(BATCH, 4), 256, 0, stream>>>(H1f, P);
    final_kernel<<<BATCH, 256, 0, stream>>>(P, W2, b2, g2, be2, m2, v2,
                                            (float*)d_out);
}

// Round 6
// 305.059 us; speedup vs baseline: 2.9284x; 1.0438x over previous
//
#include <hip/hip_runtime.h>
#include <hip/hip_bf16.h>
#include <math.h>

// Problem constants (from reference)
#define BATCH   64
#define NNODES  256
#define HID     256
#define HEADS   4
#define CDIM    64
#define NEDGES  8192
#define NEG_SLOPE 0.2f
#define EPS_BN 1e-5f

// All intermediate activations use NODE-MAJOR layout: row = node*64 + batch.

typedef __bf16 bf16_t;
typedef __bf16 bf16x8 __attribute__((ext_vector_type(8)));
typedef float  f32x4  __attribute__((ext_vector_type(4)));

__device__ __forceinline__ float gelu_f(float x) {
    return 0.5f * x * (1.0f + erff(x * 0.70710678118654752440f));
}

// ---------------------------------------------------------------------------
// Fused CSR build + weight transpose/bf16-convert. Grid 449 x 256 threads.
// Block 448: CSR by dst. Blocks 0..447: Wt[n][k] = bf16(W[k][n]).
// ---------------------------------------------------------------------------
__global__ __launch_bounds__(256) void prep_kernel(
        const int* __restrict__ ei,
        const float* __restrict__ W1, const float* __restrict__ Wa,
        const float* __restrict__ Wb, const float* __restrict__ Wc,
        const float* __restrict__ Wd,
        int* __restrict__ noff, int* __restrict__ csrc,
        bf16_t* __restrict__ T1, bf16_t* __restrict__ Ta,
        bf16_t* __restrict__ Tb, bf16_t* __restrict__ Tc,
        bf16_t* __restrict__ Td) {
    const int bx = blockIdx.x;
    const int tid = threadIdx.x;
    if (bx == 448) {
        __shared__ int cnt[NNODES];
        __shared__ int off_s[NNODES + 1];
        cnt[tid] = 0;
        __syncthreads();
        for (int e = tid; e < NEDGES; e += 256) atomicAdd(&cnt[ei[NEDGES + e]], 1);
        __syncthreads();
        if (tid == 0) {
            int s = 0;
            for (int i = 0; i < NNODES; ++i) { off_s[i] = s; s += cnt[i]; }
            off_s[NNODES] = s;
        }
        __syncthreads();
        cnt[tid] = off_s[tid];
        noff[tid] = off_s[tid];
        if (tid == 0) noff[NNODES] = off_s[NNODES];
        __syncthreads();
        for (int e = tid; e < NEDGES; e += 256) {
            int d = ei[NEDGES + e];
            int p = atomicAdd(&cnt[d], 1);
            csrc[p] = ei[e];
        }
        return;
    }
    __shared__ float tile[32][33];
    const float* in; bf16_t* out; int K, t;
    if (bx < 192) { in = W1; out = T1; K = 768; t = bx; }
    else {
        int r = bx - 192, mid = r >> 6; t = r & 63; K = 256;
        if (mid == 0) { in = Wa; out = Ta; }
        else if (mid == 1) { in = Wb; out = Tb; }
        else if (mid == 2) { in = Wc; out = Tc; }
        else { in = Wd; out = Td; }
    }
    const int kt = t >> 3, nt = t & 7;
    const int k0 = kt * 32, n0 = nt * 32;
    const int x = tid & 31, y = tid >> 5;
    #pragma unroll
    for (int j = 0; j < 4; ++j)
        tile[y + j * 8][x] = in[(size_t)(k0 + y + j * 8) * 256 + n0 + x];
    __syncthreads();
    #pragma unroll
    for (int j = 0; j < 4; ++j)
        out[(size_t)(n0 + y + j * 8) * K + k0 + x] = (bf16_t)tile[x][y + j * 8];
}

// ---------------------------------------------------------------------------
// MFMA bf16 GEMM: C[M x 256] = A[M x K] @ B[K x 256], B pre-transposed bf16.
// Tile 128(M) x 64(N), BK=32, 4 waves (2x2). All outputs bf16.
// PERM: A row = (r%64)*256+r/64 (batch-major input -> node-major output).
// DUAL: grid.x 0..3 -> C0 (bias0), 4..7 -> C1 (bias1).
// ---------------------------------------------------------------------------
#define GSTR 56

template<int A_F32, int DUAL, int EPI_BN, int PERM>
__global__ __launch_bounds__(256) void gemm_kernel(
        const void* __restrict__ Ap,
        const bf16_t* __restrict__ Bt0, const bf16_t* __restrict__ Bt1,
        bf16_t* __restrict__ C0p, bf16_t* __restrict__ C1p, int K,
        const float* __restrict__ bias0, const float* __restrict__ bias1,
        const float* __restrict__ g, const float* __restrict__ be,
        const float* __restrict__ mu, const float* __restrict__ var) {
    __shared__ bf16_t As[128][GSTR];
    __shared__ bf16_t Bs[64][GSTR];
    const int tid  = threadIdx.x;
    const int lane = tid & 63;
    const int wv   = tid >> 6;
    const int wm   = wv >> 1, wn = wv & 1;
    const int mblk = blockIdx.y * 128;
    const int nt   = blockIdx.x;
    const bool second = DUAL && (nt >= 4);
    const bf16_t* Bt = second ? Bt1 : Bt0;
    bf16_t* Cp = second ? C1p : C0p;
    const int n0 = (second ? (nt - 4) : nt) * 64;

    f32x4 acc[8];
    #pragma unroll
    for (int i = 0; i < 8; ++i) acc[i] = (f32x4){0.f, 0.f, 0.f, 0.f};

    const int arow = tid >> 1, akh = (tid & 1) * 16;
    const int gr   = mblk + arow;
    const int arr  = PERM ? ((gr & 63) * 256 + (gr >> 6)) : gr;
    const int brow = tid >> 2, bkh = (tid & 3) * 8;
    const int fm = lane & 15, kc = (lane >> 4) * 8;

    for (int k0 = 0; k0 < K; k0 += 32) {
        if (A_F32) {
            const float* ap = (const float*)Ap + (size_t)arr * K + k0 + akh;
            f32x4 a0 = *(const f32x4*)ap;
            f32x4 a1 = *(const f32x4*)(ap + 4);
            f32x4 a2 = *(const f32x4*)(ap + 8);
            f32x4 a3 = *(const f32x4*)(ap + 12);
            bf16x8 v0, v1;
            #pragma unroll
            for (int j = 0; j < 4; ++j) {
                v0[j] = (bf16_t)a0[j]; v0[4 + j] = (bf16_t)a1[j];
                v1[j] = (bf16_t)a2[j]; v1[4 + j] = (bf16_t)a3[j];
            }
            *(bf16x8*)(&As[arow][akh])     = v0;
            *(bf16x8*)(&As[arow][akh + 8]) = v1;
        } else {
            const bf16_t* ap = (const bf16_t*)Ap + (size_t)arr * K + k0 + akh;
            *(bf16x8*)(&As[arow][akh])     = *(const bf16x8*)ap;
            *(bf16x8*)(&As[arow][akh + 8]) = *(const bf16x8*)(ap + 8);
        }
        *(bf16x8*)(&Bs[brow][bkh]) =
            *(const bf16x8*)(Bt + (size_t)(n0 + brow) * K + k0 + bkh);
        __syncthreads();

        bf16x8 af[4], bf[2];
        #pragma unroll
        for (int f = 0; f < 4; ++f)
            af[f] = *(const bf16x8*)(&As[wm * 64 + f * 16 + fm][kc]);
        #pragma unroll
        for (int t = 0; t < 2; ++t)
            bf[t] = *(const bf16x8*)(&Bs[wn * 32 + t * 16 + fm][kc]);
        #pragma unroll
        for (int f = 0; f < 4; ++f)
            #pragma unroll
            for (int t = 0; t < 2; ++t)
                acc[f * 2 + t] = __builtin_amdgcn_mfma_f32_16x16x32_bf16(
                    af[f], bf[t], acc[f * 2 + t], 0, 0, 0);
        __syncthreads();
    }

    const int quad = lane >> 4, cn = lane & 15;
    #pragma unroll
    for (int t = 0; t < 2; ++t) {
        const int n = n0 + wn * 32 + t * 16 + cn;
        const float bv = second ? bias1[n] : bias0[n];
        float scale = 1.0f, shift = 0.0f;
        if (EPI_BN) {
            float s = g[n] * rsqrtf(var[n] + EPS_BN);
            scale = s;
            shift = be[n] - mu[n] * s;
        }
        #pragma unroll
        for (int f = 0; f < 4; ++f) {
            #pragma unroll
            for (int r = 0; r < 4; ++r) {
                const int m = mblk + wm * 64 + f * 16 + quad * 4 + r;
                float val = acc[f * 2 + t][r] + bv;
                if (EPI_BN) val = gelu_f(val * scale + shift);
                Cp[(size_t)m * 256 + n] = (bf16_t)val;
            }
        }
    }
}

// ---------------------------------------------------------------------------
// GATv2 edge softmax + aggregate, node-major, XCD-swizzled, 2-chain ILP.
// Grid 2048 (1-D): bg-group = bid & 7 (-> XCD-local batch slice, 1 MB L2
// footprint), node i = bid >> 3. 4 waves = 4 heads; lane = (bg=lane>>3,
// cg=lane&7: 8 ch). Two independent online-softmax chains (even/odd edges)
// hide the serial shuffle/exp latency; merged once at the end.
// lrelu(z) = 0.6z + 0.4|z|. XL/XR bf16 in, bf16 out.
// ---------------------------------------------------------------------------
__global__ __launch_bounds__(256) void edge_kernel(
        const bf16_t* __restrict__ XL, const bf16_t* __restrict__ XR,
        const float* __restrict__ att, const float* __restrict__ bo,
        const int* __restrict__ noff, const int* __restrict__ csrc,
        bf16_t* __restrict__ Hout) {
    const int bid  = blockIdx.x;
    const int i    = bid >> 3;
    const int tid  = threadIdx.x;
    const int w    = tid >> 6;
    const int lane = tid & 63;
    const int bg   = lane >> 3;
    const int cg   = lane & 7;
    const int b    = (bid & 7) * 8 + bg;
    const int cbase = w * CDIM + cg * 8;
    const size_t orow = ((size_t)i * BATCH + b) * HID + cbase;
    const float* bor = bo + cbase;

    const int s0 = noff[i], s1 = noff[i + 1];
    if (s0 == s1) {                     // uniform per block
        bf16x8 ov;
        #pragma unroll
        for (int q = 0; q < 8; ++q) ov[q] = (bf16_t)gelu_f(bor[q]);
        *(bf16x8*)(Hout + orow) = ov;
        return;
    }

    float a6[8], a4[8], xi[8];
    {
        const float* ar = att + cbase;
        const bf16x8 xr = *(const bf16x8*)(XR + orow);
        #pragma unroll
        for (int q = 0; q < 8; ++q) {
            float a = ar[q];
            a6[q] = 0.6f * a; a4[q] = 0.4f * a;
            xi[q] = (float)xr[q];
        }
    }

    const bf16_t* XLb = XL + (size_t)b * HID + cbase;
    const size_t RSTR = (size_t)BATCH * HID;

    float mA = -1e30f, dA = 0.f, mB = -1e30f, dB = 0.f;
    float accA[8], accB[8];
    #pragma unroll
    for (int q = 0; q < 8; ++q) { accA[q] = 0.f; accB[q] = 0.f; }

    int jA = csrc[s0];
    int jB = csrc[(s0 + 1 < s1) ? s0 + 1 : s0];
    bf16x8 xA = *(const bf16x8*)(XLb + (size_t)jA * RSTR);
    bf16x8 xB = *(const bf16x8*)(XLb + (size_t)jB * RSTR);

    for (int e = s0; e < s1; e += 2) {
        const int nA = (e + 2 < s1) ? e + 2 : s0;
        const int nB = (e + 3 < s1) ? e + 3 : s0;
        const int jnA = csrc[nA], jnB = csrc[nB];
        const bf16x8 xnA = *(const bf16x8*)(XLb + (size_t)jnA * RSTR);
        const bf16x8 xnB = *(const bf16x8*)(XLb + (size_t)jnB * RSTR);

        float fA[8], fB[8];
        #pragma unroll
        for (int q = 0; q < 8; ++q) { fA[q] = (float)xA[q]; fB[q] = (float)xB[q]; }
        float pA = 0.f, pB = 0.f;
        #pragma unroll
        for (int q = 0; q < 8; ++q) {
            const float zA = xi[q] + fA[q];
            const float zB = xi[q] + fB[q];
            pA = fmaf(a6[q], zA, pA);
            pB = fmaf(a6[q], zB, pB);
            pA = fmaf(a4[q], __builtin_fabsf(zA), pA);
            pB = fmaf(a4[q], __builtin_fabsf(zB), pB);
        }
        pA += __shfl_xor(pA, 1, 64);  pB += __shfl_xor(pB, 1, 64);
        pA += __shfl_xor(pA, 2, 64);  pB += __shfl_xor(pB, 2, 64);
        pA += __shfl_xor(pA, 4, 64);  pB += __shfl_xor(pB, 4, 64);

        const float mnA = fmaxf(mA, pA);
        const float alA = __expf(mA - mnA);
        const float wA  = __expf(pA - mnA);
        const float vB  = (e + 1 < s1) ? 1.f : 0.f;
        const float mnB = fmaxf(mB, pB);
        const float alB = __expf(mB - mnB);
        const float wB  = __expf(pB - mnB) * vB;
        dA = dA * alA + wA;
        dB = dB * alB + wB;
        #pragma unroll
        for (int q = 0; q < 8; ++q) {
            accA[q] = fmaf(accA[q], alA, wA * fA[q]);
            accB[q] = fmaf(accB[q], alB, wB * fB[q]);
        }
        mA = mnA; mB = mnB;
        xA = xnA; xB = xnB;
    }

    // merge chains
    const float mm = fmaxf(mA, mB);
    const float g1 = __expf(mA - mm);
    const float g2 = __expf(mB - mm);
    const float inv = 1.0f / (dA * g1 + dB * g2 + 1e-16f);
    bf16x8 ov;
    #pragma unroll
    for (int q = 0; q < 8; ++q) {
        const float o = (accA[q] * g1 + accB[q] * g2) * inv + bor[q];
        ov[q] = (bf16_t)gelu_f(o);
    }
    *(bf16x8*)(Hout + orow) = ov;
}

// ---------------------------------------------------------------------------
// Fused mean-pool + output proj: out = gelu(BN(mean_n(H1) @ W2 + b2)).
// Grid 64 (one block per batch), 256 threads. H1 node-major bf16.
// ---------------------------------------------------------------------------
__global__ __launch_bounds__(256) void pf_kernel(
        const bf16_t* __restrict__ H1, const float* __restrict__ W2,
        const float* __restrict__ b2, const float* __restrict__ g2,
        const float* __restrict__ be2, const float* __restrict__ m2,
        const float* __restrict__ v2, float* __restrict__ out) {
    __shared__ float pl[HID];
    const int b = blockIdx.x, f = threadIdx.x;
    float s = 0.f;
    for (int n = 0; n < NNODES; ++n)
        s += (float)H1[((size_t)n * BATCH + b) * HID + f];
    pl[f] = s * (1.0f / (float)NNODES);
    __syncthreads();
    float acc = 0.f;
    for (int k = 0; k < HID; ++k) acc += pl[k] * W2[(size_t)k * HID + f];
    acc += b2[f];
    const float scale = g2[f] * rsqrtf(v2[f] + EPS_BN);
    acc = (acc - m2[f]) * scale + be2[f];
    out[b * HID + f] = gelu_f(acc);
}

// ---------------------------------------------------------------------------
extern "C" void kernel_launch(void* const* d_in, const int* in_sizes, int n_in,
                              void* d_out, int out_size, void* d_ws, size_t ws_size,
                              hipStream_t stream) {
    const float* x    = (const float*)d_in[0];
    const int*   ei   = (const int*)d_in[1];
    const float* W1   = (const float*)d_in[2];
    const float* b1   = (const float*)d_in[3];
    const float* g1   = (const float*)d_in[4];
    const float* be1  = (const float*)d_in[5];
    const float* m1   = (const float*)d_in[6];
    const float* v1   = (const float*)d_in[7];
    const float* Wl0  = (const float*)d_in[8];
    const float* bl0  = (const float*)d_in[9];
    const float* Wr0  = (const float*)d_in[10];
    const float* br0  = (const float*)d_in[11];
    const float* att0 = (const float*)d_in[12];
    const float* bo0  = (const float*)d_in[13];
    const float* Wl1  = (const float*)d_in[14];
    const float* bl1  = (const float*)d_in[15];
    const float* Wr1  = (const float*)d_in[16];
    const float* br1  = (const float*)d_in[17];
    const float* att1 = (const float*)d_in[18];
    const float* bo1  = (const float*)d_in[19];
    const float* W2   = (const float*)d_in[20];
    const float* b2   = (const float*)d_in[21];
    const float* g2   = (const float*)d_in[22];
    const float* be2  = (const float*)d_in[23];
    const float* m2   = (const float*)d_in[24];
    const float* v2   = (const float*)d_in[25];

    char* ws = (char*)d_ws;
    const int M = BATCH * NNODES;                        // 16384
    const size_t SZ_BF = (size_t)M * HID * sizeof(bf16_t);   // 8 MB

    int*    noff = (int*)ws;                ws += 2048;
    int*    csrc = (int*)ws;                ws += 32768;
    bf16_t* W1t  = (bf16_t*)ws;             ws += 256 * 768 * 2;
    bf16_t* Wl0t = (bf16_t*)ws;             ws += 256 * 256 * 2;
    bf16_t* Wr0t = (bf16_t*)ws;             ws += 256 * 256 * 2;
    bf16_t* Wl1t = (bf16_t*)ws;             ws += 256 * 256 * 2;
    bf16_t* Wr1t = (bf16_t*)ws;             ws += 256 * 256 * 2;
    bf16_t* H    = (bf16_t*)ws;             ws += SZ_BF;   // node_proj out / edge1 out
    bf16_t* H2   = (bf16_t*)ws;             ws += SZ_BF;   // edge0 out
    bf16_t* XL   = (bf16_t*)ws;             ws += SZ_BF;   // lin_l out
    bf16_t* XR   = (bf16_t*)ws;             ws += SZ_BF;   // lin_r out

    prep_kernel<<<449, 256, 0, stream>>>(ei, W1, Wl0, Wr0, Wl1, Wr1,
                                         noff, csrc, W1t, Wl0t, Wr0t, Wl1t, Wr1t);

    // node_proj: H = gelu(BN(x @ W1 + b1)), batch-major A -> node-major C
    gemm_kernel<1, 0, 1, 1><<<dim3(4, 128), 256, 0, stream>>>(
        x, W1t, nullptr, H, nullptr, 768, b1, nullptr, g1, be1, m1, v1);

    // layer 0: XL = H@Wl0+bl0, XR = H@Wr0+br0 (both bf16)
    gemm_kernel<0, 1, 0, 0><<<dim3(8, 128), 256, 0, stream>>>(
        H, Wl0t, Wr0t, XL, XR, 256, bl0, br0, nullptr, nullptr, nullptr, nullptr);
    edge_kernel<<<NNODES * 8, 256, 0, stream>>>(XL, XR, att0, bo0, noff, csrc, H2);

    // layer 1
    gemm_kernel<0, 1, 0, 0><<<dim3(8, 128), 256, 0, stream>>>(
        H2, Wl1t, Wr1t, XL, XR, 256, bl1, br1, nullptr, nullptr, nullptr, nullptr);
    edge_kernel<<<NNODES * 8, 256, 0, stream>>>(XL, XR, att1, bo1, noff, csrc, H);

    pf_kernel<<<BATCH, 256, 0, stream>>>(H, W2, b2, g2, be2, m2, v2, (float*)d_out);
}